// Round 1
// baseline (118.549 us; speedup 1.0000x reference)
//
#include <hip/hip_runtime.h>
#include <math.h>

#define N_RAYS_DEFAULT 16384
#define WAVES_PER_BLOCK 4

__device__ __forceinline__ float wave_scan_mul(float v, int lane) {
#pragma unroll
    for (int off = 1; off < 64; off <<= 1) {
        float o = __shfl_up(v, off, 64);
        if (lane >= off) v *= o;
    }
    return v;
}

__device__ __forceinline__ float wave_scan_add(float v, int lane) {
#pragma unroll
    for (int off = 1; off < 64; off <<= 1) {
        float o = __shfl_up(v, off, 64);
        if (lane >= off) v += o;
    }
    return v;
}

__device__ __forceinline__ float wave_sum(float v) {
#pragma unroll
    for (int off = 32; off; off >>= 1) v += __shfl_xor(v, off, 64);
    return v;
}

__device__ __forceinline__ float softplus_f(float x) {
    // jax.nn.softplus = logaddexp(x, 0) = max(x,0) + log1p(exp(-|x|))
    return fmaxf(x, 0.0f) + log1pf(expf(-fabsf(x)));
}

__device__ __forceinline__ float sigmoid_f(float x) {
    return 1.0f / (1.0f + expf(-x));
}

// count of a[j] < x over j in [0,64)
__device__ __forceinline__ int count_lt64(const float* a, float x) {
    int lo = 0, hi = 64;
    while (lo < hi) { int mid = (lo + hi) >> 1; if (a[mid] < x) lo = mid + 1; else hi = mid; }
    return lo;
}
// count of a[j] <= x over j in [0,64)
__device__ __forceinline__ int count_le64(const float* a, float x) {
    int lo = 0, hi = 64;
    while (lo < hi) { int mid = (lo + hi) >> 1; if (a[mid] <= x) lo = mid + 1; else hi = mid; }
    return lo;
}

__global__ __launch_bounds__(WAVES_PER_BLOCK * 64)
void nerf_render_kernel(const float* __restrict__ rays_o,
                        const float* __restrict__ rays_d,
                        const float* __restrict__ W1,      // [3,64]
                        const float* __restrict__ b1,      // [64]
                        const float* __restrict__ w_sigma, // [64,1]
                        const float* __restrict__ b_sigma, // [1]
                        const float* __restrict__ W_rgb,   // [64,3]
                        const float* __restrict__ b_rgb,   // [3]
                        float* __restrict__ out)           // [N,3]
{
    const int tid  = threadIdx.x;
    const int lane = tid & 63;
    const int wv   = tid >> 6;
    const int ray  = blockIdx.x * WAVES_PER_BLOCK + wv;

    __shared__ float s_zmid[WAVES_PER_BLOCK][64];  // coarse bin centers / later: coarse z (array A)
    __shared__ float s_cdf [WAVES_PER_BLOCK][64];  // cdf / later: new_z (array B)
    __shared__ float s_zall[WAVES_PER_BLOCK][128]; // merged depths

    // ---- load + normalize ray (wave-uniform addresses -> broadcast) ----
    float ox = rays_o[ray * 3 + 0], oy = rays_o[ray * 3 + 1], oz = rays_o[ray * 3 + 2];
    float dx = rays_d[ray * 3 + 0], dy = rays_d[ray * 3 + 1], dz = rays_d[ray * 3 + 2];
    {
        float inv = 1.0f / sqrtf(dx * dx + dy * dy + dz * dz);
        dx *= inv; dy *= inv; dz *= inv;
    }

    // ---- near/far vs [-1,1]^3 cube (mirror reference arithmetic) ----
    float t0x = (-1.0f - ox) / (dx + 1e-15f);
    float t1x = ( 1.0f - ox) / (dx + 1e-15f);
    float t0y = (-1.0f - oy) / (dy + 1e-15f);
    float t1y = ( 1.0f - oy) / (dy + 1e-15f);
    float t0z = (-1.0f - oz) / (dz + 1e-15f);
    float t1z = ( 1.0f - oz) / (dz + 1e-15f);
    float nearv = fmaxf(fmaxf(fminf(t0x, t1x), fminf(t0y, t1y)), fminf(t0z, t1z));
    float farv  = fminf(fminf(fmaxf(t0x, t1x), fmaxf(t0y, t1y)), fmaxf(t0z, t1z));
    if (farv < nearv) { nearv = 1e9f; farv = 1e9f; }
    nearv = fmaxf(nearv, 0.05f);
    const float sample_dist = (farv - nearv) * (1.0f / 64.0f);

    // hoist scalar weights
    const float bs0 = b_sigma[0];
    const float br0 = b_rgb[0], br1 = b_rgb[1], br2 = b_rgb[2];

    // ---- coarse stratified samples: z = near + (far-near)*linspace(0,1,64) ----
    const float lstep = 1.0f / 63.0f;
    float z = nearv + (farv - nearv) * ((float)lane * lstep);

    float px = fminf(fmaxf(fmaf(dx, z, ox), -1.0f), 1.0f);
    float py = fminf(fmaxf(fmaf(dy, z, oy), -1.0f), 1.0f);
    float pz = fminf(fmaxf(fmaf(dz, z, oz), -1.0f), 1.0f);

    // coarse MLP: sigma only (rgb unused in coarse pass)
    float sacc = bs0;
#pragma unroll 8
    for (int j = 0; j < 64; ++j) {
        float h = fmaf(px, W1[j], fmaf(py, W1[64 + j], fmaf(pz, W1[128 + j], b1[j])));
        h = fmaxf(h, 0.0f);
        sacc = fmaf(h, w_sigma[j], sacc);
    }
    float sigma = softplus_f(sacc);

    // ---- coarse alpha compositing -> weights ----
    float z_next = __shfl_down(z, 1, 64);
    float delta  = (lane < 63) ? (z_next - z) : sample_dist;
    float alpha  = 1.0f - expf(-delta * sigma);
    float v      = 1.0f - alpha + 1e-15f;
    float incl   = wave_scan_mul(v, lane);
    float trans  = __shfl_up(incl, 1, 64);
    if (lane == 0) trans = 1.0f;
    float w = alpha * trans;

    // ---- sample_pdf over weights[1:-1] (62 entries), bins = z_mid (63) ----
    float wgt = (lane >= 1 && lane <= 62) ? (w + 1e-5f) : 0.0f;
    float total = wave_sum(wgt);
    float pdf = wgt / total;
    float cdf_incl = wave_scan_add(pdf, lane);  // lane k -> cdf[k], cdf[0]=0

    float zmid = 0.5f * (z + z_next);  // valid for lane<63
    s_zmid[wv][lane] = (lane < 63) ? zmid : 0.0f;
    s_cdf [wv][lane] = (lane < 63) ? cdf_incl : 2.0f;  // sentinel > any u
    __syncthreads();

    // u = linspace(0.5/64, 1-0.5/64, 64); step is exactly 1/64 in fp32
    float u = 0.0078125f + (float)lane * 0.015625f;
    int ind = count_le64(s_cdf[wv], u);     // searchsorted(side='right'); cdf[0]=0 => ind>=1
    int below = ind - 1;
    int above = (ind < 62) ? ind : 62;
    float cb = s_cdf[wv][below], ca = s_cdf[wv][above];
    float bb = s_zmid[wv][below], ba = s_zmid[wv][above];
    float denom = ca - cb;
    if (denom < 1e-5f) denom = 1.0f;
    float t = (u - cb) / denom;
    float nz = fmaf(t, ba - bb, bb);        // new_z, monotone nondecreasing in lane

    __syncthreads();  // done reading cdf/zmid; safe to overwrite

    // ---- merge-sort concat(z_vals, new_z) -> 128 sorted depths ----
    s_zmid[wv][lane] = z;   // array A (sorted)
    s_cdf [wv][lane] = nz;  // array B (sorted)
    __syncthreads();
    int pa = lane + count_lt64(s_cdf [wv], z);   // A-element rank (A wins ties)
    int pb = lane + count_le64(s_zmid[wv], nz);  // B-element rank
    s_zall[wv][pa] = z;
    s_zall[wv][pb] = nz;
    __syncthreads();

    float za0 = s_zall[wv][2 * lane + 0];
    float za1 = s_zall[wv][2 * lane + 1];

    // ---- fine MLP at both points: sigma + rgb ----
    float p0x = fminf(fmaxf(fmaf(dx, za0, ox), -1.0f), 1.0f);
    float p0y = fminf(fmaxf(fmaf(dy, za0, oy), -1.0f), 1.0f);
    float p0z = fminf(fmaxf(fmaf(dz, za0, oz), -1.0f), 1.0f);
    float p1x = fminf(fmaxf(fmaf(dx, za1, ox), -1.0f), 1.0f);
    float p1y = fminf(fmaxf(fmaf(dy, za1, oy), -1.0f), 1.0f);
    float p1z = fminf(fmaxf(fmaf(dz, za1, oz), -1.0f), 1.0f);

    float s0 = bs0, s1 = bs0;
    float r0 = br0, g0 = br1, bl0 = br2;
    float r1 = br0, g1 = br1, bl1 = br2;
#pragma unroll 4
    for (int j = 0; j < 64; ++j) {
        float w1x = W1[j], w1y = W1[64 + j], w1z = W1[128 + j], bj = b1[j];
        float ws  = w_sigma[j];
        float wr  = W_rgb[3 * j + 0], wg = W_rgb[3 * j + 1], wb = W_rgb[3 * j + 2];
        float h0 = fmaxf(fmaf(p0x, w1x, fmaf(p0y, w1y, fmaf(p0z, w1z, bj))), 0.0f);
        float h1 = fmaxf(fmaf(p1x, w1x, fmaf(p1y, w1y, fmaf(p1z, w1z, bj))), 0.0f);
        s0 = fmaf(h0, ws, s0);  s1 = fmaf(h1, ws, s1);
        r0 = fmaf(h0, wr, r0);  r1 = fmaf(h1, wr, r1);
        g0 = fmaf(h0, wg, g0);  g1 = fmaf(h1, wg, g1);
        bl0 = fmaf(h0, wb, bl0); bl1 = fmaf(h1, wb, bl1);
    }
    float sg0 = softplus_f(s0), sg1 = softplus_f(s1);
    r0 = sigmoid_f(r0); g0 = sigmoid_f(g0); bl0 = sigmoid_f(bl0);
    r1 = sigmoid_f(r1); g1 = sigmoid_f(g1); bl1 = sigmoid_f(bl1);

    // ---- fine compositing over 128 samples (blocked 2 per lane) ----
    float zn0 = __shfl_down(za0, 1, 64);  // z_all[2*(lane+1)]
    float d0 = za1 - za0;
    float d1 = (lane < 63) ? (zn0 - za1) : sample_dist;
    float a0 = 1.0f - expf(-d0 * sg0);
    float a1 = 1.0f - expf(-d1 * sg1);
    float v0 = 1.0f - a0 + 1e-15f;
    float v1 = 1.0f - a1 + 1e-15f;
    float local = v0 * v1;
    float incl2 = wave_scan_mul(local, lane);
    float eprod = __shfl_up(incl2, 1, 64);
    if (lane == 0) eprod = 1.0f;
    float tr0 = eprod;
    float tr1 = eprod * v0;
    float w0 = a0 * tr0;
    float w1 = a1 * tr1;

    float wsum = wave_sum(w0 + w1);
    float rs = wave_sum(fmaf(w0, r0,  w1 * r1));
    float gs = wave_sum(fmaf(w0, g0,  w1 * g1));
    float bs = wave_sum(fmaf(w0, bl0, w1 * bl1));

    if (lane == 0) {
        float bg = 1.0f - wsum;
        out[ray * 3 + 0] = rs + bg;
        out[ray * 3 + 1] = gs + bg;
        out[ray * 3 + 2] = bs + bg;
    }
}

extern "C" void kernel_launch(void* const* d_in, const int* in_sizes, int n_in,
                              void* d_out, int out_size, void* d_ws, size_t ws_size,
                              hipStream_t stream) {
    const float* rays_o  = (const float*)d_in[0];
    const float* rays_d  = (const float*)d_in[1];
    const float* W1      = (const float*)d_in[2];
    const float* b1      = (const float*)d_in[3];
    const float* w_sigma = (const float*)d_in[4];
    const float* b_sigma = (const float*)d_in[5];
    const float* W_rgb   = (const float*)d_in[6];
    const float* b_rgb   = (const float*)d_in[7];
    float* out = (float*)d_out;

    const int n_rays = in_sizes[0] / 3;
    dim3 grid((n_rays + WAVES_PER_BLOCK - 1) / WAVES_PER_BLOCK);
    dim3 block(WAVES_PER_BLOCK * 64);
    hipLaunchKernelGGL(nerf_render_kernel, grid, block, 0, stream,
                       rays_o, rays_d, W1, b1, w_sigma, b_sigma, W_rgb, b_rgb, out);
}

// Round 2
// 104.584 us; speedup vs baseline: 1.1335x; 1.1335x over previous
//
#include <hip/hip_runtime.h>
#include <math.h>

#define WAVES_PER_BLOCK 4

typedef float v2f __attribute__((ext_vector_type(2)));

__device__ __forceinline__ v2f v2_fma(v2f a, v2f b, v2f c) {
    return __builtin_elementwise_fma(a, b, c);
}
__device__ __forceinline__ v2f v2_max0(v2f a) {
    return __builtin_elementwise_max(a, (v2f){0.0f, 0.0f});
}
__device__ __forceinline__ v2f v2_splat(float x) { return (v2f){x, x}; }

__device__ __forceinline__ float fast_rcp(float x) { return __builtin_amdgcn_rcpf(x); }

__device__ __forceinline__ float wave_scan_mul(float v, int lane) {
#pragma unroll
    for (int off = 1; off < 64; off <<= 1) {
        float o = __shfl_up(v, off, 64);
        if (lane >= off) v *= o;
    }
    return v;
}

__device__ __forceinline__ float wave_scan_add(float v, int lane) {
#pragma unroll
    for (int off = 1; off < 64; off <<= 1) {
        float o = __shfl_up(v, off, 64);
        if (lane >= off) v += o;
    }
    return v;
}

__device__ __forceinline__ float wave_sum(float v) {
#pragma unroll
    for (int off = 32; off; off >>= 1) v += __shfl_xor(v, off, 64);
    return v;
}

__device__ __forceinline__ float softplus_f(float x) {
    // log(1+e^x) = max(x,0) + log(1 + e^-|x|); native exp/log (~1ulp, fine vs 2e-2)
    return fmaxf(x, 0.0f) + __logf(1.0f + __expf(-fabsf(x)));
}

__device__ __forceinline__ float sigmoid_f(float x) {
    return fast_rcp(1.0f + __expf(-x));
}

// count of a[j] < x over j in [0,64)
__device__ __forceinline__ int count_lt64(const float* a, float x) {
    int lo = 0, hi = 64;
    while (lo < hi) { int mid = (lo + hi) >> 1; if (a[mid] < x) lo = mid + 1; else hi = mid; }
    return lo;
}
// count of a[j] <= x over j in [0,64)
__device__ __forceinline__ int count_le64(const float* a, float x) {
    int lo = 0, hi = 64;
    while (lo < hi) { int mid = (lo + hi) >> 1; if (a[mid] <= x) lo = mid + 1; else hi = mid; }
    return lo;
}

__global__ __launch_bounds__(WAVES_PER_BLOCK * 64)
void nerf_render_kernel(const float* __restrict__ rays_o,
                        const float* __restrict__ rays_d,
                        const float* __restrict__ W1,      // [3,64]
                        const float* __restrict__ b1,      // [64]
                        const float* __restrict__ w_sigma, // [64,1]
                        const float* __restrict__ b_sigma, // [1]
                        const float* __restrict__ W_rgb,   // [64,3]
                        const float* __restrict__ b_rgb,   // [3]
                        float* __restrict__ out)           // [N,3]
{
    const int tid  = threadIdx.x;
    const int lane = tid & 63;
    const int wv   = tid >> 6;
    const int ray  = blockIdx.x * WAVES_PER_BLOCK + wv;

    __shared__ float s_zmid[WAVES_PER_BLOCK][64];  // bin centers / later: coarse z (A)
    __shared__ float s_cdf [WAVES_PER_BLOCK][64];  // cdf / later: new_z (B)
    __shared__ float s_zall[WAVES_PER_BLOCK][128]; // merged depths

    // ---- load + normalize ray (wave-uniform -> scalar broadcast) ----
    float ox = rays_o[ray * 3 + 0], oy = rays_o[ray * 3 + 1], oz = rays_o[ray * 3 + 2];
    float dx = rays_d[ray * 3 + 0], dy = rays_d[ray * 3 + 1], dz = rays_d[ray * 3 + 2];
    {
        float inv = __builtin_amdgcn_rsqf(dx * dx + dy * dy + dz * dz);
        dx *= inv; dy *= inv; dz *= inv;
    }

    // ---- near/far vs [-1,1]^3 cube (rcp instead of divide) ----
    float rx = fast_rcp(dx + 1e-15f);
    float ry = fast_rcp(dy + 1e-15f);
    float rz = fast_rcp(dz + 1e-15f);
    float t0x = (-1.0f - ox) * rx, t1x = (1.0f - ox) * rx;
    float t0y = (-1.0f - oy) * ry, t1y = (1.0f - oy) * ry;
    float t0z = (-1.0f - oz) * rz, t1z = (1.0f - oz) * rz;
    float nearv = fmaxf(fmaxf(fminf(t0x, t1x), fminf(t0y, t1y)), fminf(t0z, t1z));
    float farv  = fminf(fminf(fmaxf(t0x, t1x), fmaxf(t0y, t1y)), fmaxf(t0z, t1z));
    if (farv < nearv) { nearv = 1e9f; farv = 1e9f; }
    nearv = fmaxf(nearv, 0.05f);
    const float sample_dist = (farv - nearv) * (1.0f / 64.0f);

    const float bs0 = b_sigma[0];
    const float br0 = b_rgb[0], br1 = b_rgb[1], br2 = b_rgb[2];

    // ---- coarse stratified samples ----
    const float lstep = 1.0f / 63.0f;
    float z = nearv + (farv - nearv) * ((float)lane * lstep);

    float px = fminf(fmaxf(fmaf(dx, z, ox), -1.0f), 1.0f);
    float py = fminf(fmaxf(fmaf(dy, z, oy), -1.0f), 1.0f);
    float pz = fminf(fmaxf(fmaf(dz, z, oz), -1.0f), 1.0f);

    // ---- coarse MLP (sigma only), packed over hidden-unit pairs ----
    const v2f* W1x2 = (const v2f*)(W1);        // [32]
    const v2f* W1y2 = (const v2f*)(W1 + 64);
    const v2f* W1z2 = (const v2f*)(W1 + 128);
    const v2f* b12  = (const v2f*)(b1);
    const v2f* ws2  = (const v2f*)(w_sigma);

    v2f px2 = v2_splat(px), py2 = v2_splat(py), pz2 = v2_splat(pz);
    v2f sacc2 = (v2f){bs0, 0.0f};
#pragma unroll 8
    for (int j = 0; j < 32; ++j) {
        v2f h = v2_fma(px2, W1x2[j], v2_fma(py2, W1y2[j], v2_fma(pz2, W1z2[j], b12[j])));
        h = v2_max0(h);
        sacc2 = v2_fma(h, ws2[j], sacc2);
    }
    float sigma = softplus_f(sacc2.x + sacc2.y);

    // ---- coarse alpha compositing -> weights ----
    float z_next = __shfl_down(z, 1, 64);
    float delta  = (lane < 63) ? (z_next - z) : sample_dist;
    float alpha  = 1.0f - __expf(-delta * sigma);
    float v      = 1.0f - alpha + 1e-15f;
    float incl   = wave_scan_mul(v, lane);
    float trans  = __shfl_up(incl, 1, 64);
    if (lane == 0) trans = 1.0f;
    float w = alpha * trans;

    // ---- sample_pdf over weights[1:-1], bins = z_mid ----
    float wgt = (lane >= 1 && lane <= 62) ? (w + 1e-5f) : 0.0f;
    float total = wave_sum(wgt);
    float pdf = wgt * fast_rcp(total);
    float cdf_incl = wave_scan_add(pdf, lane);

    float zmid = 0.5f * (z + z_next);
    s_zmid[wv][lane] = (lane < 63) ? zmid : 0.0f;
    s_cdf [wv][lane] = (lane < 63) ? cdf_incl : 2.0f;  // sentinel
    __syncthreads();

    float u = 0.0078125f + (float)lane * 0.015625f;
    int ind = count_le64(s_cdf[wv], u);
    int below = ind - 1;
    int above = (ind < 62) ? ind : 62;
    float cb = s_cdf[wv][below], ca = s_cdf[wv][above];
    float bb = s_zmid[wv][below], ba = s_zmid[wv][above];
    float denom = ca - cb;
    if (denom < 1e-5f) denom = 1.0f;
    float t = (u - cb) * fast_rcp(denom);
    float nz = fmaf(t, ba - bb, bb);

    __syncthreads();

    // ---- rank-merge concat(z, new_z) -> 128 sorted ----
    s_zmid[wv][lane] = z;
    s_cdf [wv][lane] = nz;
    __syncthreads();
    int pa = lane + count_lt64(s_cdf [wv], z);
    int pb = lane + count_le64(s_zmid[wv], nz);
    s_zall[wv][pa] = z;
    s_zall[wv][pb] = nz;
    __syncthreads();

    float za0 = s_zall[wv][2 * lane + 0];
    float za1 = s_zall[wv][2 * lane + 1];

    // ---- fine MLP at both points, packed over the sample pair ----
    v2f pxx = { fminf(fmaxf(fmaf(dx, za0, ox), -1.0f), 1.0f),
                fminf(fmaxf(fmaf(dx, za1, ox), -1.0f), 1.0f) };
    v2f pyy = { fminf(fmaxf(fmaf(dy, za0, oy), -1.0f), 1.0f),
                fminf(fmaxf(fmaf(dy, za1, oy), -1.0f), 1.0f) };
    v2f pzz = { fminf(fmaxf(fmaf(dz, za0, oz), -1.0f), 1.0f),
                fminf(fmaxf(fmaf(dz, za1, oz), -1.0f), 1.0f) };

    v2f s2 = v2_splat(bs0);
    v2f r2 = v2_splat(br0), g2 = v2_splat(br1), bch2 = v2_splat(br2);
#pragma unroll 8
    for (int j = 0; j < 64; ++j) {
        float w1x = W1[j], w1y = W1[64 + j], w1z = W1[128 + j], bj = b1[j];
        float ws  = w_sigma[j];
        float wr  = W_rgb[3 * j + 0], wg = W_rgb[3 * j + 1], wb = W_rgb[3 * j + 2];
        v2f h = v2_fma(pxx, v2_splat(w1x),
                v2_fma(pyy, v2_splat(w1y),
                v2_fma(pzz, v2_splat(w1z), v2_splat(bj))));
        h = v2_max0(h);
        s2   = v2_fma(h, v2_splat(ws), s2);
        r2   = v2_fma(h, v2_splat(wr), r2);
        g2   = v2_fma(h, v2_splat(wg), g2);
        bch2 = v2_fma(h, v2_splat(wb), bch2);
    }
    float sg0 = softplus_f(s2.x), sg1 = softplus_f(s2.y);
    float r0 = sigmoid_f(r2.x),   r1 = sigmoid_f(r2.y);
    float g0 = sigmoid_f(g2.x),   g1 = sigmoid_f(g2.y);
    float bl0 = sigmoid_f(bch2.x), bl1 = sigmoid_f(bch2.y);

    // ---- fine compositing over 128 samples (2/lane) ----
    float zn0 = __shfl_down(za0, 1, 64);
    float d0 = za1 - za0;
    float d1 = (lane < 63) ? (zn0 - za1) : sample_dist;
    float a0 = 1.0f - __expf(-d0 * sg0);
    float a1 = 1.0f - __expf(-d1 * sg1);
    float v0 = 1.0f - a0 + 1e-15f;
    float v1 = 1.0f - a1 + 1e-15f;
    float local = v0 * v1;
    float incl2 = wave_scan_mul(local, lane);
    float eprod = __shfl_up(incl2, 1, 64);
    if (lane == 0) eprod = 1.0f;
    float tr0 = eprod;
    float tr1 = eprod * v0;
    float w0 = a0 * tr0;
    float w1 = a1 * tr1;

    float wsum = wave_sum(w0 + w1);
    float rs = wave_sum(fmaf(w0, r0,  w1 * r1));
    float gs = wave_sum(fmaf(w0, g0,  w1 * g1));
    float bs = wave_sum(fmaf(w0, bl0, w1 * bl1));

    if (lane == 0) {
        float bg = 1.0f - wsum;
        out[ray * 3 + 0] = rs + bg;
        out[ray * 3 + 1] = gs + bg;
        out[ray * 3 + 2] = bs + bg;
    }
}

extern "C" void kernel_launch(void* const* d_in, const int* in_sizes, int n_in,
                              void* d_out, int out_size, void* d_ws, size_t ws_size,
                              hipStream_t stream) {
    const float* rays_o  = (const float*)d_in[0];
    const float* rays_d  = (const float*)d_in[1];
    const float* W1      = (const float*)d_in[2];
    const float* b1      = (const float*)d_in[3];
    const float* w_sigma = (const float*)d_in[4];
    const float* b_sigma = (const float*)d_in[5];
    const float* W_rgb   = (const float*)d_in[6];
    const float* b_rgb   = (const float*)d_in[7];
    float* out = (float*)d_out;

    const int n_rays = in_sizes[0] / 3;
    dim3 grid((n_rays + WAVES_PER_BLOCK - 1) / WAVES_PER_BLOCK);
    dim3 block(WAVES_PER_BLOCK * 64);
    hipLaunchKernelGGL(nerf_render_kernel, grid, block, 0, stream,
                       rays_o, rays_d, W1, b1, w_sigma, b_sigma, W_rgb, b_rgb, out);
}

// Round 3
// 96.967 us; speedup vs baseline: 1.2226x; 1.0786x over previous
//
#include <hip/hip_runtime.h>
#include <math.h>

#define WAVES_PER_BLOCK 4

typedef float v2f __attribute__((ext_vector_type(2)));

__device__ __forceinline__ v2f v2_fma(v2f a, v2f b, v2f c) {
    return __builtin_elementwise_fma(a, b, c);
}
__device__ __forceinline__ v2f v2_max0(v2f a) {
    return __builtin_elementwise_max(a, (v2f){0.0f, 0.0f});
}
__device__ __forceinline__ v2f v2_splat(float x) { return (v2f){x, x}; }

__device__ __forceinline__ float fast_rcp(float x) { return __builtin_amdgcn_rcpf(x); }

__device__ __forceinline__ float wave_scan_mul(float v, int lane) {
#pragma unroll
    for (int off = 1; off < 64; off <<= 1) {
        float o = __shfl_up(v, off, 64);
        if (lane >= off) v *= o;
    }
    return v;
}

__device__ __forceinline__ float wave_scan_add(float v, int lane) {
#pragma unroll
    for (int off = 1; off < 64; off <<= 1) {
        float o = __shfl_up(v, off, 64);
        if (lane >= off) v += o;
    }
    return v;
}

__device__ __forceinline__ float wave_sum(float v) {
#pragma unroll
    for (int off = 32; off; off >>= 1) v += __shfl_xor(v, off, 64);
    return v;
}

// packed 2-float reduction: same ds_bpermute count, half the adds
__device__ __forceinline__ v2f wave_sum2(v2f v) {
#pragma unroll
    for (int off = 32; off; off >>= 1) {
        v2f o = { __shfl_xor(v.x, off, 64), __shfl_xor(v.y, off, 64) };
        v += o;
    }
    return v;
}

__device__ __forceinline__ float softplus_f(float x) {
    return fmaxf(x, 0.0f) + __logf(1.0f + __expf(-fabsf(x)));
}

__device__ __forceinline__ float sigmoid_f(float x) {
    return fast_rcp(1.0f + __expf(-x));
}

__device__ __forceinline__ float clamp1(float x) {
    return fminf(fmaxf(x, -1.0f), 1.0f);
}

// count of a[j] < x over j in [0,64)
__device__ __forceinline__ int count_lt64(const float* a, float x) {
    int lo = 0, hi = 64;
    while (lo < hi) { int mid = (lo + hi) >> 1; if (a[mid] < x) lo = mid + 1; else hi = mid; }
    return lo;
}
// count of a[j] <= x over j in [0,64)
__device__ __forceinline__ int count_le64(const float* a, float x) {
    int lo = 0, hi = 64;
    while (lo < hi) { int mid = (lo + hi) >> 1; if (a[mid] <= x) lo = mid + 1; else hi = mid; }
    return lo;
}

__global__ __launch_bounds__(WAVES_PER_BLOCK * 64)
void nerf_render_kernel(const float* __restrict__ rays_o,
                        const float* __restrict__ rays_d,
                        const float* __restrict__ W1,      // [3,64]
                        const float* __restrict__ b1,      // [64]
                        const float* __restrict__ w_sigma, // [64,1]
                        const float* __restrict__ b_sigma, // [1]
                        const float* __restrict__ W_rgb,   // [64,3]
                        const float* __restrict__ b_rgb,   // [3]
                        float* __restrict__ out)           // [N,3]
{
    const int tid  = threadIdx.x;
    const int lane = tid & 63;
    const int wv   = tid >> 6;
    const int ray  = blockIdx.x * WAVES_PER_BLOCK + wv;

    __shared__ float s_cm  [WAVES_PER_BLOCK][128]; // c[0..63], m[64..127] per ray
    __shared__ float s_zmid[WAVES_PER_BLOCK][64];
    __shared__ float s_cdf [WAVES_PER_BLOCK][64];
    __shared__ float s_zall[WAVES_PER_BLOCK][128];

    // ---- ray load + normalize ----
    float ox = rays_o[ray * 3 + 0], oy = rays_o[ray * 3 + 1], oz = rays_o[ray * 3 + 2];
    float dx = rays_d[ray * 3 + 0], dy = rays_d[ray * 3 + 1], dz = rays_d[ray * 3 + 2];
    {
        float inv = __builtin_amdgcn_rsqf(dx * dx + dy * dy + dz * dz);
        dx *= inv; dy *= inv; dz *= inv;
    }

    // ---- near/far vs [-1,1]^3 ----
    float rx = fast_rcp(dx + 1e-15f);
    float ry = fast_rcp(dy + 1e-15f);
    float rz = fast_rcp(dz + 1e-15f);
    float t0x = (-1.0f - ox) * rx, t1x = (1.0f - ox) * rx;
    float t0y = (-1.0f - oy) * ry, t1y = (1.0f - oy) * ry;
    float t0z = (-1.0f - oz) * rz, t1z = (1.0f - oz) * rz;
    float nearv = fmaxf(fmaxf(fminf(t0x, t1x), fminf(t0y, t1y)), fminf(t0z, t1z));
    float farv  = fminf(fminf(fmaxf(t0x, t1x), fmaxf(t0y, t1y)), fmaxf(t0z, t1z));
    const bool miss = (farv < nearv);       // wave-uniform in practice
    if (miss) { nearv = 1e9f; farv = 1e9f; }
    nearv = fmaxf(nearv, 0.05f);
    const float sample_dist = (farv - nearv) * (1.0f / 64.0f);

    const float bs0 = b_sigma[0];
    const float br0 = b_rgb[0], br1 = b_rgb[1], br2 = b_rgb[2];

    // ---- per-ray affine layer-1 coefficients: a_j(z) = c_j + m_j*z ----
    // All sampled points lie inside the cube (z in [near,far] subset of
    // [entry,exit]) so clip() is a no-op and the pre-activation is affine.
    // Miss rays: z==1e9 for all samples, point = clamp(o + 1e9*d) -> encode
    // as m_j = 0 exactly, c_j = MLP pre-act at that clamped corner.
    {
        float w1x = W1[lane], w1y = W1[64 + lane], w1z = W1[128 + lane];
        float eox = ox, eoy = oy, eoz = oz, msc = 1.0f;
        if (miss) {
            eox = clamp1(fmaf(dx, 1e9f, ox));
            eoy = clamp1(fmaf(dy, 1e9f, oy));
            eoz = clamp1(fmaf(dz, 1e9f, oz));
            msc = 0.0f;
        }
        float cj = fmaf(eox, w1x, fmaf(eoy, w1y, fmaf(eoz, w1z, b1[lane])));
        float mj = msc * fmaf(dx, w1x, fmaf(dy, w1y, dz * w1z));
        s_cm[wv][lane]      = cj;
        s_cm[wv][64 + lane] = mj;
        // intra-wave LDS RAW: DS ops execute in program order per wave and the
        // compiler must preserve order on may-alias LDS ops; no barrier needed
        // (each wave touches only its own [wv] slice).
    }

    // ---- coarse samples ----
    float z = nearv + (farv - nearv) * ((float)lane * (1.0f / 63.0f));

    // ---- coarse MLP (sigma only): h_j = relu(m_j*z + c_j), packed pairs ----
    const v2f* c2p = (const v2f*)&s_cm[wv][0];
    const v2f* m2p = (const v2f*)&s_cm[wv][64];
    const v2f* ws2 = (const v2f*)w_sigma;
    v2f z2 = v2_splat(z);
    v2f acc = (v2f){bs0, 0.0f};
#pragma unroll 8
    for (int jj = 0; jj < 32; ++jj) {
        v2f h = v2_max0(v2_fma(m2p[jj], z2, c2p[jj]));
        acc = v2_fma(h, ws2[jj], acc);
    }
    float sigma = softplus_f(acc.x + acc.y);

    // ---- coarse alpha compositing -> weights ----
    float z_next = __shfl_down(z, 1, 64);
    float delta  = (lane < 63) ? (z_next - z) : sample_dist;
    float alpha  = 1.0f - __expf(-delta * sigma);
    float v      = 1.0f - alpha + 1e-15f;
    float incl   = wave_scan_mul(v, lane);
    float trans  = __shfl_up(incl, 1, 64);
    if (lane == 0) trans = 1.0f;
    float w = alpha * trans;

    // ---- sample_pdf over weights[1:-1], bins = z_mid ----
    float wgt = (lane >= 1 && lane <= 62) ? (w + 1e-5f) : 0.0f;
    float total = wave_sum(wgt);
    float pdf = wgt * fast_rcp(total);
    float cdf_incl = wave_scan_add(pdf, lane);

    float zmid = 0.5f * (z + z_next);
    s_zmid[wv][lane] = (lane < 63) ? zmid : 0.0f;
    s_cdf [wv][lane] = (lane < 63) ? cdf_incl : 2.0f;  // sentinel
    __syncthreads();

    float u = 0.0078125f + (float)lane * 0.015625f;
    int ind = count_le64(s_cdf[wv], u);
    int below = ind - 1;
    int above = (ind < 62) ? ind : 62;
    float cb = s_cdf[wv][below], ca = s_cdf[wv][above];
    float bb = s_zmid[wv][below], ba = s_zmid[wv][above];
    float denom = ca - cb;
    if (denom < 1e-5f) denom = 1.0f;
    float t = (u - cb) * fast_rcp(denom);
    float nz = fmaf(t, ba - bb, bb);

    __syncthreads();

    // ---- rank-merge concat(z, new_z) -> 128 sorted ----
    s_zmid[wv][lane] = z;
    s_cdf [wv][lane] = nz;
    __syncthreads();
    int pa = lane + count_lt64(s_cdf [wv], z);
    int pb = lane + count_le64(s_zmid[wv], nz);
    s_zall[wv][pa] = z;
    s_zall[wv][pb] = nz;
    __syncthreads();

    float za0 = s_zall[wv][2 * lane + 0];
    float za1 = s_zall[wv][2 * lane + 1];

    // ---- fine MLP at both points via affine layer-1, packed over samples ----
    v2f zz = (v2f){za0, za1};
    v2f s2 = v2_splat(bs0);
    v2f r2 = v2_splat(br0), g2 = v2_splat(br1), bch2 = v2_splat(br2);
#pragma unroll 8
    for (int j = 0; j < 64; ++j) {
        float cj = s_cm[wv][j];        // uniform addr -> broadcast
        float mj = s_cm[wv][64 + j];
        v2f h = v2_max0(v2_fma(v2_splat(mj), zz, v2_splat(cj)));
        s2   = v2_fma(h, v2_splat(w_sigma[j]),    s2);
        r2   = v2_fma(h, v2_splat(W_rgb[3 * j + 0]), r2);
        g2   = v2_fma(h, v2_splat(W_rgb[3 * j + 1]), g2);
        bch2 = v2_fma(h, v2_splat(W_rgb[3 * j + 2]), bch2);
    }
    float sg0 = softplus_f(s2.x), sg1 = softplus_f(s2.y);
    float r0 = sigmoid_f(r2.x),   r1 = sigmoid_f(r2.y);
    float g0 = sigmoid_f(g2.x),   g1 = sigmoid_f(g2.y);
    float bl0 = sigmoid_f(bch2.x), bl1 = sigmoid_f(bch2.y);

    // ---- fine compositing over 128 samples (2/lane) ----
    float zn0 = __shfl_down(za0, 1, 64);
    float d0 = za1 - za0;
    float d1 = (lane < 63) ? (zn0 - za1) : sample_dist;
    float a0 = 1.0f - __expf(-d0 * sg0);
    float a1 = 1.0f - __expf(-d1 * sg1);
    float v0 = 1.0f - a0 + 1e-15f;
    float v1 = 1.0f - a1 + 1e-15f;
    float local = v0 * v1;
    float incl2 = wave_scan_mul(local, lane);
    float eprod = __shfl_up(incl2, 1, 64);
    if (lane == 0) eprod = 1.0f;
    float w0 = a0 * eprod;
    float w1 = a1 * (eprod * v0);

    v2f wr_ = { w0 + w1,               fmaf(w0, r0,  w1 * r1) };
    v2f gb_ = { fmaf(w0, g0, w1 * g1), fmaf(w0, bl0, w1 * bl1) };
    wr_ = wave_sum2(wr_);
    gb_ = wave_sum2(gb_);

    if (lane == 0) {
        float bg = 1.0f - wr_.x;
        out[ray * 3 + 0] = wr_.y + bg;
        out[ray * 3 + 1] = gb_.x + bg;
        out[ray * 3 + 2] = gb_.y + bg;
    }
}

extern "C" void kernel_launch(void* const* d_in, const int* in_sizes, int n_in,
                              void* d_out, int out_size, void* d_ws, size_t ws_size,
                              hipStream_t stream) {
    const float* rays_o  = (const float*)d_in[0];
    const float* rays_d  = (const float*)d_in[1];
    const float* W1      = (const float*)d_in[2];
    const float* b1      = (const float*)d_in[3];
    const float* w_sigma = (const float*)d_in[4];
    const float* b_sigma = (const float*)d_in[5];
    const float* W_rgb   = (const float*)d_in[6];
    const float* b_rgb   = (const float*)d_in[7];
    float* out = (float*)d_out;

    const int n_rays = in_sizes[0] / 3;
    dim3 grid((n_rays + WAVES_PER_BLOCK - 1) / WAVES_PER_BLOCK);
    dim3 block(WAVES_PER_BLOCK * 64);
    hipLaunchKernelGGL(nerf_render_kernel, grid, block, 0, stream,
                       rays_o, rays_d, W1, b1, w_sigma, b_sigma, W_rgb, b_rgb, out);
}

// Round 4
// 96.059 us; speedup vs baseline: 1.2341x; 1.0094x over previous
//
#include <hip/hip_runtime.h>
#include <math.h>

#define WAVES_PER_BLOCK 4

typedef float v2f __attribute__((ext_vector_type(2)));
typedef float v4f __attribute__((ext_vector_type(4)));

__device__ __forceinline__ v2f v2_fma(v2f a, v2f b, v2f c) {
    return __builtin_elementwise_fma(a, b, c);
}
__device__ __forceinline__ v2f v2_max0(v2f a) {
    return __builtin_elementwise_max(a, (v2f){0.0f, 0.0f});
}
__device__ __forceinline__ v2f v2_splat(float x) { return (v2f){x, x}; }

__device__ __forceinline__ float fast_rcp(float x) { return __builtin_amdgcn_rcpf(x); }

// ---------------- DPP cross-lane primitives (no LDS, ~2cyc) ----------------
#define DPP_ROW_SHR(n)  (0x110 | (n))
#define DPP_WF_SL1      0x130   /* lane i <- lane i+1 (shfl_down 1) */
#define DPP_WF_SR1      0x138   /* lane i <- lane i-1 (shfl_up 1)   */
#define DPP_ROW_BCAST15 0x142
#define DPP_ROW_BCAST31 0x143

template <int CTRL, int RM = 0xf, int BM = 0xf, bool BC = false>
__device__ __forceinline__ float fdpp(float old_, float src) {
    return __int_as_float(__builtin_amdgcn_update_dpp(
        __float_as_int(old_), __float_as_int(src), CTRL, RM, BM, BC));
}

__device__ __forceinline__ float lane63_bcast(float x) {
    return __int_as_float(__builtin_amdgcn_readlane(__float_as_int(x), 63));
}

// inclusive scan-add across 64 lanes (canonical gfx9 DPP sequence)
__device__ __forceinline__ float scan_add_dpp(float x) {
    x += fdpp<DPP_ROW_SHR(1)>(0.0f, x);
    x += fdpp<DPP_ROW_SHR(2)>(0.0f, x);
    x += fdpp<DPP_ROW_SHR(4)>(0.0f, x);
    x += fdpp<DPP_ROW_SHR(8)>(0.0f, x);
    x += fdpp<DPP_ROW_BCAST15, 0xa>(0.0f, x);
    x += fdpp<DPP_ROW_BCAST31, 0xc>(0.0f, x);
    return x;
}
// inclusive scan-mul across 64 lanes (identity = 1.0)
__device__ __forceinline__ float scan_mul_dpp(float x) {
    x *= fdpp<DPP_ROW_SHR(1)>(1.0f, x);
    x *= fdpp<DPP_ROW_SHR(2)>(1.0f, x);
    x *= fdpp<DPP_ROW_SHR(4)>(1.0f, x);
    x *= fdpp<DPP_ROW_SHR(8)>(1.0f, x);
    x *= fdpp<DPP_ROW_BCAST15, 0xa>(1.0f, x);
    x *= fdpp<DPP_ROW_BCAST31, 0xc>(1.0f, x);
    return x;
}
__device__ __forceinline__ float wave_sum_dpp(float x) {
    return lane63_bcast(scan_add_dpp(x));
}

__device__ __forceinline__ float softplus_f(float x) {
    return fmaxf(x, 0.0f) + __logf(1.0f + __expf(-fabsf(x)));
}
__device__ __forceinline__ float sigmoid_f(float x) {
    return fast_rcp(1.0f + __expf(-x));
}
__device__ __forceinline__ float clamp1(float x) {
    return fminf(fmaxf(x, -1.0f), 1.0f);
}

// count of a[j] < x over j in [0,64)
__device__ __forceinline__ int count_lt64(const float* a, float x) {
    int lo = 0, hi = 64;
    while (lo < hi) { int mid = (lo + hi) >> 1; if (a[mid] < x) lo = mid + 1; else hi = mid; }
    return lo;
}
// count of a[j] <= x over j in [0,64)
__device__ __forceinline__ int count_le64(const float* a, float x) {
    int lo = 0, hi = 64;
    while (lo < hi) { int mid = (lo + hi) >> 1; if (a[mid] <= x) lo = mid + 1; else hi = mid; }
    return lo;
}

__global__ __launch_bounds__(WAVES_PER_BLOCK * 64)
void nerf_render_kernel(const float* __restrict__ rays_o,
                        const float* __restrict__ rays_d,
                        const float* __restrict__ W1,      // [3,64]
                        const float* __restrict__ b1,      // [64]
                        const float* __restrict__ w_sigma, // [64,1]
                        const float* __restrict__ b_sigma, // [1]
                        const float* __restrict__ W_rgb,   // [64,3]
                        const float* __restrict__ b_rgb,   // [3]
                        float* __restrict__ out)           // [N,3]
{
    const int tid  = threadIdx.x;
    const int lane = tid & 63;
    const int wv   = tid >> 6;
    const int ray  = blockIdx.x * WAVES_PER_BLOCK + wv;

    // (c,m) in 16B granules: [4t..4t+3] = {c_{2t}, c_{2t+1}, m_{2t}, m_{2t+1}}
    __shared__ float s_cm  [WAVES_PER_BLOCK][128];
    __shared__ float s_zmid[WAVES_PER_BLOCK][64];
    __shared__ float s_cdf [WAVES_PER_BLOCK][64];
    __shared__ float s_zall[WAVES_PER_BLOCK][128];

    // ---- ray load + normalize ----
    float ox = rays_o[ray * 3 + 0], oy = rays_o[ray * 3 + 1], oz = rays_o[ray * 3 + 2];
    float dx = rays_d[ray * 3 + 0], dy = rays_d[ray * 3 + 1], dz = rays_d[ray * 3 + 2];
    {
        float inv = __builtin_amdgcn_rsqf(dx * dx + dy * dy + dz * dz);
        dx *= inv; dy *= inv; dz *= inv;
    }

    // ---- near/far vs [-1,1]^3 ----
    float rx = fast_rcp(dx + 1e-15f);
    float ry = fast_rcp(dy + 1e-15f);
    float rz = fast_rcp(dz + 1e-15f);
    float t0x = (-1.0f - ox) * rx, t1x = (1.0f - ox) * rx;
    float t0y = (-1.0f - oy) * ry, t1y = (1.0f - oy) * ry;
    float t0z = (-1.0f - oz) * rz, t1z = (1.0f - oz) * rz;
    float nearv = fmaxf(fmaxf(fminf(t0x, t1x), fminf(t0y, t1y)), fminf(t0z, t1z));
    float farv  = fminf(fminf(fmaxf(t0x, t1x), fmaxf(t0y, t1y)), fmaxf(t0z, t1z));
    const bool miss = (farv < nearv);
    if (miss) { nearv = 1e9f; farv = 1e9f; }
    nearv = fmaxf(nearv, 0.05f);
    const float sample_dist = (farv - nearv) * (1.0f / 64.0f);

    const float bs0 = b_sigma[0];
    const float br0 = b_rgb[0], br1 = b_rgb[1], br2 = b_rgb[2];

    // ---- per-ray affine layer-1: a_j(z) = c_j + m_j*z (clip is a no-op for
    // in-cube samples; miss rays use m=0, c at clamped corner) ----
    {
        float w1x = W1[lane], w1y = W1[64 + lane], w1z = W1[128 + lane];
        float eox = ox, eoy = oy, eoz = oz, msc = 1.0f;
        if (miss) {
            eox = clamp1(fmaf(dx, 1e9f, ox));
            eoy = clamp1(fmaf(dy, 1e9f, oy));
            eoz = clamp1(fmaf(dz, 1e9f, oz));
            msc = 0.0f;
        }
        float cj = fmaf(eox, w1x, fmaf(eoy, w1y, fmaf(eoz, w1z, b1[lane])));
        float mj = msc * fmaf(dx, w1x, fmaf(dy, w1y, dz * w1z));
        int g = (lane >> 1) * 4 + (lane & 1);
        s_cm[wv][g]     = cj;
        s_cm[wv][g + 2] = mj;
        // intra-wave RAW on own slice: DS ops are program-ordered per wave.
    }

    // ---- coarse samples ----
    float z = nearv + (farv - nearv) * ((float)lane * (1.0f / 63.0f));

    // ---- coarse MLP (sigma only): h = relu(m*z + c), b128 granules ----
    const v2f* ws2 = (const v2f*)w_sigma;
    v2f z2 = v2_splat(z);
    v2f acc = (v2f){bs0, 0.0f};
#pragma unroll 8
    for (int t = 0; t < 32; ++t) {
        v4f g = *(const v4f*)&s_cm[wv][4 * t];
        v2f h = v2_max0(v2_fma((v2f){g.z, g.w}, z2, (v2f){g.x, g.y}));
        acc = v2_fma(h, ws2[t], acc);
    }
    float sigma = softplus_f(acc.x + acc.y);

    // ---- coarse alpha compositing -> weights ----
    float z_next = fdpp<DPP_WF_SL1>(0.0f, z);
    float delta  = (lane < 63) ? (z_next - z) : sample_dist;
    float alpha  = 1.0f - __expf(-delta * sigma);
    float v      = 1.0f - alpha + 1e-15f;
    float incl   = scan_mul_dpp(v);
    float trans  = fdpp<DPP_WF_SR1>(1.0f, incl);   // lane0 -> 1.0
    float w = alpha * trans;

    // ---- sample_pdf: unnormalized scan, total from lane63 of same scan ----
    float wgt = (lane >= 1 && lane <= 62) ? (w + 1e-5f) : 0.0f;
    float cumw = scan_add_dpp(wgt);
    float total = lane63_bcast(cumw);
    float cdf_incl = cumw * fast_rcp(total);

    float zmid = 0.5f * (z + z_next);
    s_zmid[wv][lane] = (lane < 63) ? zmid : 0.0f;
    s_cdf [wv][lane] = (lane < 63) ? cdf_incl : 2.0f;  // sentinel
    __syncthreads();

    float u = 0.0078125f + (float)lane * 0.015625f;
    int ind = count_le64(s_cdf[wv], u);
    int below = ind - 1;
    int above = (ind < 62) ? ind : 62;
    float cb = s_cdf[wv][below], ca = s_cdf[wv][above];
    float bb = s_zmid[wv][below], ba = s_zmid[wv][above];
    float denom = ca - cb;
    if (denom < 1e-5f) denom = 1.0f;
    float t = (u - cb) * fast_rcp(denom);
    float nz = fmaf(t, ba - bb, bb);

    __syncthreads();

    // ---- rank-merge concat(z, new_z) -> 128 sorted ----
    s_zmid[wv][lane] = z;
    s_cdf [wv][lane] = nz;
    __syncthreads();
    int pa = lane + count_lt64(s_cdf [wv], z);
    int pb = lane + count_le64(s_zmid[wv], nz);
    s_zall[wv][pa] = z;
    s_zall[wv][pb] = nz;
    __syncthreads();

    float za0 = s_zall[wv][2 * lane + 0];
    float za1 = s_zall[wv][2 * lane + 1];

    // ---- fine MLP at both points, packed over sample pair, b128 granules ----
    v2f zz = (v2f){za0, za1};
    v2f s2 = v2_splat(bs0);
    v2f r2 = v2_splat(br0), g2 = v2_splat(br1), bch2 = v2_splat(br2);
#pragma unroll 8
    for (int t = 0; t < 32; ++t) {
        v4f g = *(const v4f*)&s_cm[wv][4 * t];
        int j0 = 2 * t, j1 = 2 * t + 1;
        v2f h0 = v2_max0(v2_fma(v2_splat(g.z), zz, v2_splat(g.x)));
        s2   = v2_fma(h0, v2_splat(w_sigma[j0]),       s2);
        r2   = v2_fma(h0, v2_splat(W_rgb[3 * j0 + 0]), r2);
        g2   = v2_fma(h0, v2_splat(W_rgb[3 * j0 + 1]), g2);
        bch2 = v2_fma(h0, v2_splat(W_rgb[3 * j0 + 2]), bch2);
        v2f h1 = v2_max0(v2_fma(v2_splat(g.w), zz, v2_splat(g.y)));
        s2   = v2_fma(h1, v2_splat(w_sigma[j1]),       s2);
        r2   = v2_fma(h1, v2_splat(W_rgb[3 * j1 + 0]), r2);
        g2   = v2_fma(h1, v2_splat(W_rgb[3 * j1 + 1]), g2);
        bch2 = v2_fma(h1, v2_splat(W_rgb[3 * j1 + 2]), bch2);
    }
    float sg0 = softplus_f(s2.x), sg1 = softplus_f(s2.y);
    float r0 = sigmoid_f(r2.x),   r1 = sigmoid_f(r2.y);
    float g0 = sigmoid_f(g2.x),   g1 = sigmoid_f(g2.y);
    float bl0 = sigmoid_f(bch2.x), bl1 = sigmoid_f(bch2.y);

    // ---- fine compositing over 128 samples (2/lane) ----
    float zn0 = fdpp<DPP_WF_SL1>(0.0f, za0);
    float d0 = za1 - za0;
    float d1 = (lane < 63) ? (zn0 - za1) : sample_dist;
    float a0 = 1.0f - __expf(-d0 * sg0);
    float a1 = 1.0f - __expf(-d1 * sg1);
    float v0 = 1.0f - a0 + 1e-15f;
    float v1 = 1.0f - a1 + 1e-15f;
    float local = v0 * v1;
    float incl2 = scan_mul_dpp(local);
    float eprod = fdpp<DPP_WF_SR1>(1.0f, incl2);   // lane0 -> 1.0
    float w0 = a0 * eprod;
    float w1 = a1 * (eprod * v0);

    float wsum = wave_sum_dpp(w0 + w1);
    float rs   = wave_sum_dpp(fmaf(w0, r0,  w1 * r1));
    float gs   = wave_sum_dpp(fmaf(w0, g0,  w1 * g1));
    float bs   = wave_sum_dpp(fmaf(w0, bl0, w1 * bl1));

    if (lane == 0) {
        float bg = 1.0f - wsum;
        out[ray * 3 + 0] = rs + bg;
        out[ray * 3 + 1] = gs + bg;
        out[ray * 3 + 2] = bs + bg;
    }
}

extern "C" void kernel_launch(void* const* d_in, const int* in_sizes, int n_in,
                              void* d_out, int out_size, void* d_ws, size_t ws_size,
                              hipStream_t stream) {
    const float* rays_o  = (const float*)d_in[0];
    const float* rays_d  = (const float*)d_in[1];
    const float* W1      = (const float*)d_in[2];
    const float* b1      = (const float*)d_in[3];
    const float* w_sigma = (const float*)d_in[4];
    const float* b_sigma = (const float*)d_in[5];
    const float* W_rgb   = (const float*)d_in[6];
    const float* b_rgb   = (const float*)d_in[7];
    float* out = (float*)d_out;

    const int n_rays = in_sizes[0] / 3;
    dim3 grid((n_rays + WAVES_PER_BLOCK - 1) / WAVES_PER_BLOCK);
    dim3 block(WAVES_PER_BLOCK * 64);
    hipLaunchKernelGGL(nerf_render_kernel, grid, block, 0, stream,
                       rays_o, rays_d, W1, b1, w_sigma, b_sigma, W_rgb, b_rgb, out);
}